// Round 6
// baseline (914.941 us; speedup 1.0000x reference)
//
#include <hip/hip_runtime.h>

// Sizes: N=500000, C=128, H=256, A=10, E=600000, B=50000.
// R6: k_gemm reg-resident W^T + double-buffered A + swapped MFMA operands.
// R7: LDS-transpose gemm epilogue; CSR graph; readout restructure.
// R8: launch_bounds(256,1) on gemm — NEUTRAL -> spill theory refuted.
// R9: fixed-K=8 inline adjacency replacing CSR; merged tconv; 7 dispatches
//     (-16us: scan/scatter overhead ~ CSR gain).
// R10 (this round): MEASUREMENT ROUND. k_readout launched 4x (idempotent:
//   writes only xB, no atomics -> bit-identical output). Kernels unchanged.
//   Delta vs R9 = 3 x t_readout(warm), resolving the attribution that the
//   1GB poison-fills (~153us) have occluded since R2. If t_readout >= ~157us
//   the duplicates also surface in top-5 with full counters.

typedef __bf16 bf16x8 __attribute__((ext_vector_type(8)));
typedef __bf16 bf16x4 __attribute__((ext_vector_type(4)));
typedef float f32x4 __attribute__((ext_vector_type(4)));

// ---- per-edge: degree + direct K=8 adjacency write (+ rare overflow) --------
__global__ __launch_bounds__(256) void k_edges(const int* __restrict__ dst,
                                               const int* __restrict__ src, int E,
                                               int* __restrict__ deg,
                                               int* __restrict__ adj,
                                               int* __restrict__ ovfc,
                                               int* __restrict__ ovf) {
    int e = blockIdx.x * 256 + threadIdx.x;
    if (e < E) {
        int d = dst[e];
        int s = src[e];
        int slot = atomicAdd(&deg[d], 1);
        if (slot < 8) {
            adj[(size_t)d * 8 + slot] = s;
        } else {
            int o = atomicAdd(ovfc, 1);
            ovf[2 * o] = d;
            ovf[2 * o + 1] = s;
        }
    }
}

// ---- dinv = rsqrt(deg + 1)  (+1 = self loop) --------------------------------
__global__ __launch_bounds__(256) void k_dinv(const int* __restrict__ deg,
                                              float* __restrict__ dinv, int N) {
    int i = blockIdx.x * 256 + threadIdx.x;
    if (i < N) dinv[i] = rsqrtf((float)deg[i] + 1.0f);
}

// ---- transpose-convert all three weight matrices in one launch --------------
// ranges: [0,16384) Wgcn 128x128 | [16384,49152) W1 128x256 | rest W2 256x256
__global__ __launch_bounds__(256) void k_tconv_all(const float* __restrict__ Wg,
                                                   const float* __restrict__ W1,
                                                   const float* __restrict__ W2,
                                                   __bf16* __restrict__ Wgt,
                                                   __bf16* __restrict__ W1t,
                                                   __bf16* __restrict__ W2t) {
    int i = blockIdx.x * 256 + threadIdx.x;
    if (i < 16384) {
        int n = i >> 7, k = i & 127;
        Wgt[i] = (__bf16)Wg[k * 128 + n];
    } else if (i < 49152) {
        int j = i - 16384;
        int n = j >> 7, k = j & 127;
        W1t[j] = (__bf16)W1[k * 256 + n];
    } else if (i < 114688) {
        int j = i - 49152;
        int n = j >> 8, k = j & 255;
        W2t[j] = (__bf16)W2[k * 256 + n];
    }
}

// ---- xws = bf16( dinv[row] * (state @ W_gcn) )  via MFMA 16x16x32 bf16 ------
__global__ __launch_bounds__(256, 1) void k_gemm(const float* __restrict__ X,
                                                 const __bf16* __restrict__ Wt,
                                                 const float* __restrict__ dinv,
                                                 __bf16* __restrict__ Y, int N) {
    __shared__ __bf16 st[4][16][136];   // per-wave transpose staging, +8 pad
    int wave = threadIdx.x >> 6;
    int lane = threadIdx.x & 63;
    int m = lane & 15;
    int quad = lane >> 4;
    const long NT = (long)N >> 4;                  // 16-row tiles
    const long g0 = (long)blockIdx.x * 4 + wave;   // global wave id
    const long gs = (long)gridDim.x * 4;
    if (g0 >= NT) return;

    // W^T fragments resident for the whole kernel (128 VGPRs).
    bf16x8 bfrag[8][4];
    #pragma unroll
    for (int t = 0; t < 8; t++)
        #pragma unroll
        for (int kt = 0; kt < 4; kt++)
            bfrag[t][kt] =
                *(const bf16x8*)(Wt + (t * 16 + m) * 128 + kt * 32 + quad * 8);

    auto loadA = [&](float4* BUF, long tile) {
        const float* ap = X + (tile * 16 + m) * 128 + quad * 8;
        #pragma unroll
        for (int kt = 0; kt < 4; kt++) {
            BUF[2 * kt]     = *(const float4*)(ap + kt * 32);
            BUF[2 * kt + 1] = *(const float4*)(ap + kt * 32 + 4);
        }
    };

    auto compute = [&](const float4* BUF, long tile) {
        long row = tile * 16 + m;
        float dv = dinv[row];
        f32x4 acc[8] = {};
        #pragma unroll
        for (int kt = 0; kt < 4; kt++) {
            float4 lo = BUF[2 * kt], hi = BUF[2 * kt + 1];
            bf16x8 a = {(__bf16)lo.x, (__bf16)lo.y, (__bf16)lo.z, (__bf16)lo.w,
                        (__bf16)hi.x, (__bf16)hi.y, (__bf16)hi.z, (__bf16)hi.w};
            #pragma unroll
            for (int t = 0; t < 8; t++)
                acc[t] = __builtin_amdgcn_mfma_f32_16x16x32_bf16(bfrag[t][kt], a,
                                                                 acc[t], 0, 0, 0);
        }
        // stage lane-owned row m into LDS, then read back row-major and store
        // 4 rows x 256B = 1KB fully-coalesced per instruction.
        #pragma unroll
        for (int t = 0; t < 8; t++) {
            bf16x4 o;
            #pragma unroll
            for (int r = 0; r < 4; r++) o[r] = (__bf16)(acc[t][r] * dv);
            *(bf16x4*)&st[wave][m][t * 16 + quad * 4] = o;
        }
        asm volatile("s_waitcnt lgkmcnt(0)" ::: "memory");
        __builtin_amdgcn_sched_barrier(0);
        #pragma unroll
        for (int it = 0; it < 4; it++) {
            bf16x8 v = *(const bf16x8*)&st[wave][it * 4 + quad][m * 8];
            *(bf16x8*)(Y + (tile * 16 + it * 4 + quad) * 128 + m * 8) = v;
        }
    };

    float4 A0[8], A1[8];
    loadA(A0, g0);
    long t = g0;
    while (true) {
        long t1 = t + gs;
        loadA(A1, t1 < NT ? t1 : t);      // clamped dummy prefetch at tail
        compute(A0, t);
        if (t1 >= NT) break;
        long t2 = t1 + gs;
        loadA(A0, t2 < NT ? t2 : t1);
        compute(A1, t1);
        if (t2 >= NT) break;
        t = t2;
    }
}

// ---- fused aggregate + relu + residual + action-weighted readout ------------
// 256 thr = 16 slots x 16 lanes. Block handles 8 b's; slot pair (2s,2s+1)
// covers b_local = s: slot handles nodes b*10 + (slot&1)*5 + k, k<5.
__global__ __launch_bounds__(256) void k_readout(const int* __restrict__ deg,
                                                 const int* __restrict__ adj,
                                                 const int* __restrict__ ovfc,
                                                 const int* __restrict__ ovf,
                                                 const float* __restrict__ dinv,
                                                 const __bf16* __restrict__ xws,
                                                 const float* __restrict__ state,
                                                 const float* __restrict__ bgcn,
                                                 const float* __restrict__ action,
                                                 __bf16* __restrict__ xB, int B) {
    __shared__ float red[16][132];
    int tid = threadIdx.x;
    int slot = tid >> 4;
    int lane16 = tid & 15;
    int c0 = lane16 * 8;
    int b = blockIdx.x * 8 + (slot >> 1);

    float4 bg0 = *(const float4*)(bgcn + c0);
    float4 bg1 = *(const float4*)(bgcn + c0 + 4);
    float bg[8] = {bg0.x, bg0.y, bg0.z, bg0.w, bg1.x, bg1.y, bg1.z, bg1.w};
    float acc[8] = {};

    if (b < B) {
        int nbase = b * 10 + (slot & 1) * 5;
        // prefetch degree + adjacency for all 5 nodes (independent loads)
        int dgs[5];
        int4 aj0[5], aj1[5];
        #pragma unroll
        for (int k = 0; k < 5; k++) {
            int n = nbase + k;
            dgs[k] = deg[n];
            aj0[k] = *(const int4*)(adj + (size_t)n * 8);
            aj1[k] = *(const int4*)(adj + (size_t)n * 8 + 4);
        }
        #pragma unroll
        for (int k = 0; k < 5; k++) {
            int n = nbase + k;
            int dg = dgs[k];
            bf16x8 x = *(const bf16x8*)(xws + (size_t)n * 128 + c0);
            float s[8];
            #pragma unroll
            for (int i = 0; i < 8; i++) s[i] = (float)x[i];
            int nb[8] = {aj0[k].x, aj0[k].y, aj0[k].z, aj0[k].w,
                         aj1[k].x, aj1[k].y, aj1[k].z, aj1[k].w};
            #pragma unroll
            for (int j = 0; j < 8; j++) {
                if (j < dg) {
                    bf16x8 g = *(const bf16x8*)(xws + (size_t)nb[j] * 128 + c0);
                    #pragma unroll
                    for (int i = 0; i < 8; i++) s[i] += (float)g[i];
                }
            }
            if (dg > 8) {             // ~2-3 nodes in 500K: scan overflow list
                int c = *ovfc;
                for (int o = 0; o < c; o++) {
                    if (ovf[2 * o] == n) {
                        bf16x8 g =
                            *(const bf16x8*)(xws + (size_t)ovf[2 * o + 1] * 128 + c0);
                        #pragma unroll
                        for (int i = 0; i < 8; i++) s[i] += (float)g[i];
                    }
                }
            }
            float di = dinv[n];
            float aw = action[n] * 10.f;
            float4 st0 = *(const float4*)(state + (size_t)n * 128 + c0);
            float4 st1 = *(const float4*)(state + (size_t)n * 128 + c0 + 4);
            float stv[8] = {st0.x, st0.y, st0.z, st0.w,
                            st1.x, st1.y, st1.z, st1.w};
            #pragma unroll
            for (int i = 0; i < 8; i++)
                acc[i] += aw * (fmaxf(di * s[i] + bg[i], 0.f) + stv[i]);
        }
    }
    f32x4 va = {acc[0], acc[1], acc[2], acc[3]};
    f32x4 vb = {acc[4], acc[5], acc[6], acc[7]};
    *(f32x4*)&red[slot][c0] = va;
    *(f32x4*)&red[slot][c0 + 4] = vb;
    __syncthreads();
    // 8 b x 128 ch outputs; thread t: b_local = t>>5, 4 consecutive channels
    int bl = tid >> 5;
    int ch0 = (tid & 31) * 4;
    int b2 = blockIdx.x * 8 + bl;
    if (b2 < B) {
        bf16x4 o;
        #pragma unroll
        for (int c = 0; c < 4; c++)
            o[c] = (__bf16)(red[2 * bl][ch0 + c] + red[2 * bl + 1][ch0 + c]);
        *(bf16x4*)(xB + (size_t)b2 * 128 + ch0) = o;
    }
}

// ---- MLP head via MFMA: relu(x@W1+b1) -> relu(@W2+b2) -> @W3+b3 -------------
__global__ __launch_bounds__(256) void k_mlp(const __bf16* __restrict__ xB,
                                             const __bf16* __restrict__ W1t,
                                             const float* __restrict__ b1,
                                             const __bf16* __restrict__ W2t,
                                             const float* __restrict__ b2,
                                             const float* __restrict__ W3,
                                             const float* __restrict__ b3,
                                             float* __restrict__ out, int B) {
    __shared__ __bf16 hs[16][264];
    __shared__ float osum[4][16];
    int wave = threadIdx.x >> 6;
    int lane = threadIdx.x & 63;
    int m = lane & 15;
    int quad = lane >> 4;
    long r0 = (long)blockIdx.x * 16;

    f32x4 acc[4] = {};
    #pragma unroll
    for (int kt = 0; kt < 4; kt++) {
        int k0 = kt * 32 + quad * 8;
        bf16x8 a = *(const bf16x8*)(xB + (r0 + m) * 128 + k0);
        #pragma unroll
        for (int t = 0; t < 4; t++) {
            int n = wave * 64 + t * 16 + m;
            bf16x8 b = *(const bf16x8*)(W1t + (long)n * 128 + k0);
            acc[t] = __builtin_amdgcn_mfma_f32_16x16x32_bf16(a, b, acc[t], 0, 0, 0);
        }
    }
    #pragma unroll
    for (int t = 0; t < 4; t++) {
        int n = wave * 64 + t * 16 + m;
        float bb = b1[n];
        #pragma unroll
        for (int r = 0; r < 4; r++)
            hs[quad * 4 + r][n] = (__bf16)fmaxf(acc[t][r] + bb, 0.f);
    }
    __syncthreads();

    f32x4 acc2[4] = {};
    #pragma unroll
    for (int kt = 0; kt < 8; kt++) {
        int k0 = kt * 32 + quad * 8;
        bf16x8 a = *(const bf16x8*)(&hs[m][k0]);
        #pragma unroll
        for (int t = 0; t < 4; t++) {
            int n = wave * 64 + t * 16 + m;
            bf16x8 b = *(const bf16x8*)(W2t + (long)n * 256 + k0);
            acc2[t] = __builtin_amdgcn_mfma_f32_16x16x32_bf16(a, b, acc2[t], 0, 0, 0);
        }
    }

    float part[4] = {0.f, 0.f, 0.f, 0.f};
    #pragma unroll
    for (int t = 0; t < 4; t++) {
        int n = wave * 64 + t * 16 + m;
        float bb = b2[n], w3 = W3[n];
        #pragma unroll
        for (int r = 0; r < 4; r++)
            part[r] += fmaxf(acc2[t][r] + bb, 0.f) * w3;
    }
    #pragma unroll
    for (int off = 8; off; off >>= 1)
        #pragma unroll
        for (int r = 0; r < 4; r++)
            part[r] += __shfl_down(part[r], off, 16);
    if (m == 0) {
        #pragma unroll
        for (int r = 0; r < 4; r++) osum[wave][quad * 4 + r] = part[r];
    }
    __syncthreads();
    if (threadIdx.x < 16)
        out[r0 + threadIdx.x] = osum[0][threadIdx.x] + osum[1][threadIdx.x] +
                                osum[2][threadIdx.x] + osum[3][threadIdx.x] + b3[0];
}

extern "C" void kernel_launch(void* const* d_in, const int* in_sizes, int n_in,
                              void* d_out, int out_size, void* d_ws, size_t ws_size,
                              hipStream_t stream) {
    const float* state  = (const float*)d_in[0];
    const int*   edge   = (const int*)d_in[1];   // [2, E]: src row then dst row
    const float* action = (const float*)d_in[2];
    const float* W_gcn  = (const float*)d_in[3];
    const float* b_gcn  = (const float*)d_in[4];
    const float* W1     = (const float*)d_in[5];
    const float* b1     = (const float*)d_in[6];
    const float* W2     = (const float*)d_in[7];
    const float* b2     = (const float*)d_in[8];
    const float* W3     = (const float*)d_in[9];
    const float* b3     = (const float*)d_in[10];
    float* out = (float*)d_out;

    int N = in_sizes[0] / 128;
    int E = in_sizes[1] / 2;
    int B = out_size;
    const int* e_src = edge;
    const int* e_dst = edge + E;

    // workspace layout (16B-aligned for the given sizes):
    // xws bf16[N*128] | xB bf16[B*128] | Wgt bf16[128*128] | W1t bf16[256*128]
    // | W2t bf16[256*256] | dinv f32[N] | deg i32[N] | ovfc i32[4]
    // | adj i32[N*8] | ovf i32[2*E]
    __bf16* xws = (__bf16*)d_ws;
    __bf16* xB  = xws + (size_t)N * 128;
    __bf16* Wgt = xB + (size_t)B * 128;
    __bf16* W1t = Wgt + 128 * 128;
    __bf16* W2t = W1t + 256 * 128;
    float* dinv = (float*)(W2t + 256 * 256);
    int*   deg  = (int*)(dinv + N);
    int*   ovfc = deg + N;
    int*   adj  = ovfc + 4;
    int*   ovf  = adj + (size_t)N * 8;

    // zero deg + ovfc in one memset
    hipMemsetAsync(deg, 0, ((size_t)N + 4) * sizeof(int), stream);

    k_tconv_all<<<448, 256, 0, stream>>>(W_gcn, W1, W2, Wgt, W1t, W2t);
    k_edges<<<(E + 255) / 256, 256, 0, stream>>>(e_dst, e_src, E, deg, adj, ovfc, ovf);
    k_dinv<<<(N + 255) / 256, 256, 0, stream>>>(deg, dinv, N);
    k_gemm<<<1024, 256, 0, stream>>>(state, Wgt, dinv, xws, N);
    // MEASUREMENT: 4 identical idempotent launches; delta vs R9 = 3x t_readout.
    k_readout<<<(B + 7) / 8, 256, 0, stream>>>(deg, adj, ovfc, ovf, dinv, xws,
                                               state, b_gcn, action, xB, B);
    k_readout<<<(B + 7) / 8, 256, 0, stream>>>(deg, adj, ovfc, ovf, dinv, xws,
                                               state, b_gcn, action, xB, B);
    k_readout<<<(B + 7) / 8, 256, 0, stream>>>(deg, adj, ovfc, ovf, dinv, xws,
                                               state, b_gcn, action, xB, B);
    k_readout<<<(B + 7) / 8, 256, 0, stream>>>(deg, adj, ovfc, ovf, dinv, xws,
                                               state, b_gcn, action, xB, B);
    k_mlp<<<B / 16, 256, 0, stream>>>(xB, W1t, b1, W2t, b2, W3, b3, out, B);
}

// Round 7
// 686.443 us; speedup vs baseline: 1.3329x; 1.3329x over previous
//
#include <hip/hip_runtime.h>

// Sizes: N=500000, C=128, H=256, A=10, E=600000, B=50000.
// R6: k_gemm reg-resident W^T + dbuf A + swapped MFMA operands (177->~123us).
// R7: CSR graph; readout restructure. R8: (256,1) NEUTRAL (spill refuted).
// R9: fixed-K=8 inline adjacency; merged tconv (-16us).
// R10: measurement: t_readout = 99us (= near its ~90us traffic floor).
// R11 (this round): k_gemm occupancy rewrite. Theory: reg-resident W (~250
//   VGPR) capped occupancy at 2 waves/SIMD; serial chain (vmcnt ~900cy +
//   MFMA 160cy + epilogue lgkm stall) under-hidden -> 123us vs 60us floor.
//   Change: W^T in 32KB XOR-swizzled LDS (byte^=(row&7)<<4, both sides,
//   balanced 8-words/bank b128 reads), single-buffer A, direct 8B stores,
//   __launch_bounds__(256,4) -> ~110 VGPR, 4 waves/SIMD, 16 waves/CU.
//   Also: k_dinv deleted (rsqrt(deg+1) inlined in gemm + readout).

typedef __bf16 bf16x8 __attribute__((ext_vector_type(8)));
typedef __bf16 bf16x4 __attribute__((ext_vector_type(4)));
typedef float f32x4 __attribute__((ext_vector_type(4)));

// ---- per-edge: degree + direct K=8 adjacency write (+ rare overflow) --------
__global__ __launch_bounds__(256) void k_edges(const int* __restrict__ dst,
                                               const int* __restrict__ src, int E,
                                               int* __restrict__ deg,
                                               int* __restrict__ adj,
                                               int* __restrict__ ovfc,
                                               int* __restrict__ ovf) {
    int e = blockIdx.x * 256 + threadIdx.x;
    if (e < E) {
        int d = dst[e];
        int s = src[e];
        int slot = atomicAdd(&deg[d], 1);
        if (slot < 8) {
            adj[(size_t)d * 8 + slot] = s;
        } else {
            int o = atomicAdd(ovfc, 1);
            ovf[2 * o] = d;
            ovf[2 * o + 1] = s;
        }
    }
}

// ---- transpose-convert all three weight matrices in one launch --------------
// ranges: [0,16384) Wgcn 128x128 | [16384,49152) W1 128x256 | rest W2 256x256
__global__ __launch_bounds__(256) void k_tconv_all(const float* __restrict__ Wg,
                                                   const float* __restrict__ W1,
                                                   const float* __restrict__ W2,
                                                   __bf16* __restrict__ Wgt,
                                                   __bf16* __restrict__ W1t,
                                                   __bf16* __restrict__ W2t) {
    int i = blockIdx.x * 256 + threadIdx.x;
    if (i < 16384) {
        int n = i >> 7, k = i & 127;
        Wgt[i] = (__bf16)Wg[k * 128 + n];
    } else if (i < 49152) {
        int j = i - 16384;
        int n = j >> 7, k = j & 127;
        W1t[j] = (__bf16)W1[k * 256 + n];
    } else if (i < 114688) {
        int j = i - 49152;
        int n = j >> 8, k = j & 255;
        W2t[j] = (__bf16)W2[k * 256 + n];
    }
}

// ---- xws = bf16( rsqrt(deg+1)[row] * (state @ W_gcn) )  via MFMA ------------
// 4 waves/block, grid-stride over 16-row tiles. W^T staged once per block into
// XOR-swizzled LDS; A single-buffered (TLP hides latency at 4 waves/SIMD).
__global__ __launch_bounds__(256, 4) void k_gemm(const float* __restrict__ X,
                                                 const __bf16* __restrict__ Wt,
                                                 const int* __restrict__ deg,
                                                 __bf16* __restrict__ Y, int N) {
    __shared__ __bf16 wlds[128 * 128];   // 32KB, XOR-swizzled rows
    int tid = threadIdx.x;
    int wave = tid >> 6;
    int lane = tid & 63;
    int m = lane & 15;
    int quad = lane >> 4;

    // stage W^T: thread covers row n = tid>>1, half h = tid&1 (128B each).
    // LDS byte addr within row: chunk^((n&7)<<4)  (involution, both sides).
    {
        int n = tid >> 1, h = tid & 1;
        const __bf16* gsrc = Wt + n * 128 + h * 64;
        char* wb = (char*)wlds + n * 256;
        int xm = (n & 7) << 4;
        #pragma unroll
        for (int j = 0; j < 8; j++) {
            bf16x8 v = *(const bf16x8*)(gsrc + j * 8);
            *(bf16x8*)(wb + ((h * 128 + j * 16) ^ xm)) = v;
        }
    }
    __syncthreads();

    const long NT = (long)N >> 4;                  // 31250 tiles
    const long g0 = (long)blockIdx.x * 4 + wave;
    const long gs = (long)gridDim.x * 4;
    const int xm = (m & 7) << 4;                   // read-side swizzle mask

    for (long tile = g0; tile < NT; tile += gs) {
        long row = tile * 16 + m;
        const float* ap = X + row * 128 + quad * 8;
        float4 BUF[8];
        #pragma unroll
        for (int kt = 0; kt < 4; kt++) {
            BUF[2 * kt]     = *(const float4*)(ap + kt * 32);
            BUF[2 * kt + 1] = *(const float4*)(ap + kt * 32 + 4);
        }
        float dv = rsqrtf((float)deg[row] + 1.0f);

        f32x4 acc[8] = {};
        #pragma unroll
        for (int kt = 0; kt < 4; kt++) {
            float4 lo = BUF[2 * kt], hi = BUF[2 * kt + 1];
            bf16x8 a = {(__bf16)lo.x, (__bf16)lo.y, (__bf16)lo.z, (__bf16)lo.w,
                        (__bf16)hi.x, (__bf16)hi.y, (__bf16)hi.z, (__bf16)hi.w};
            #pragma unroll
            for (int t = 0; t < 8; t++) {
                const bf16x8 bf = *(const bf16x8*)((const char*)wlds +
                    ((t * 16 + m) << 8) + ((kt * 64 + quad * 16) ^ xm));
                acc[t] = __builtin_amdgcn_mfma_f32_16x16x32_bf16(bf, a,
                                                                 acc[t], 0, 0, 0);
            }
        }
        __bf16* yp = Y + row * 128 + quad * 4;
        #pragma unroll
        for (int t = 0; t < 8; t++) {
            bf16x4 o;
            #pragma unroll
            for (int r = 0; r < 4; r++) o[r] = (__bf16)(acc[t][r] * dv);
            *(bf16x4*)(yp + t * 16) = o;
        }
    }
}

// ---- fused aggregate + relu + residual + action-weighted readout ------------
// 256 thr = 16 slots x 16 lanes. Block handles 8 b's; slot pair (2s,2s+1)
// covers b_local = s: slot handles nodes b*10 + (slot&1)*5 + k, k<5.
__global__ __launch_bounds__(256) void k_readout(const int* __restrict__ deg,
                                                 const int* __restrict__ adj,
                                                 const int* __restrict__ ovfc,
                                                 const int* __restrict__ ovf,
                                                 const __bf16* __restrict__ xws,
                                                 const float* __restrict__ state,
                                                 const float* __restrict__ bgcn,
                                                 const float* __restrict__ action,
                                                 __bf16* __restrict__ xB, int B) {
    __shared__ float red[16][132];
    int tid = threadIdx.x;
    int slot = tid >> 4;
    int lane16 = tid & 15;
    int c0 = lane16 * 8;
    int b = blockIdx.x * 8 + (slot >> 1);

    float4 bg0 = *(const float4*)(bgcn + c0);
    float4 bg1 = *(const float4*)(bgcn + c0 + 4);
    float bg[8] = {bg0.x, bg0.y, bg0.z, bg0.w, bg1.x, bg1.y, bg1.z, bg1.w};
    float acc[8] = {};

    if (b < B) {
        int nbase = b * 10 + (slot & 1) * 5;
        // prefetch degree + adjacency for all 5 nodes (independent loads)
        int dgs[5];
        int4 aj0[5], aj1[5];
        #pragma unroll
        for (int k = 0; k < 5; k++) {
            int n = nbase + k;
            dgs[k] = deg[n];
            aj0[k] = *(const int4*)(adj + (size_t)n * 8);
            aj1[k] = *(const int4*)(adj + (size_t)n * 8 + 4);
        }
        #pragma unroll
        for (int k = 0; k < 5; k++) {
            int n = nbase + k;
            int dg = dgs[k];
            bf16x8 x = *(const bf16x8*)(xws + (size_t)n * 128 + c0);
            float s[8];
            #pragma unroll
            for (int i = 0; i < 8; i++) s[i] = (float)x[i];
            int nb[8] = {aj0[k].x, aj0[k].y, aj0[k].z, aj0[k].w,
                         aj1[k].x, aj1[k].y, aj1[k].z, aj1[k].w};
            #pragma unroll
            for (int j = 0; j < 8; j++) {
                if (j < dg) {
                    bf16x8 g = *(const bf16x8*)(xws + (size_t)nb[j] * 128 + c0);
                    #pragma unroll
                    for (int i = 0; i < 8; i++) s[i] += (float)g[i];
                }
            }
            if (dg > 8) {             // ~2-3 nodes in 500K: scan overflow list
                int c = *ovfc;
                for (int o = 0; o < c; o++) {
                    if (ovf[2 * o] == n) {
                        bf16x8 g =
                            *(const bf16x8*)(xws + (size_t)ovf[2 * o + 1] * 128 + c0);
                        #pragma unroll
                        for (int i = 0; i < 8; i++) s[i] += (float)g[i];
                    }
                }
            }
            float di = rsqrtf((float)dg + 1.0f);
            float aw = action[n] * 10.f;
            float4 st0 = *(const float4*)(state + (size_t)n * 128 + c0);
            float4 st1 = *(const float4*)(state + (size_t)n * 128 + c0 + 4);
            float stv[8] = {st0.x, st0.y, st0.z, st0.w,
                            st1.x, st1.y, st1.z, st1.w};
            #pragma unroll
            for (int i = 0; i < 8; i++)
                acc[i] += aw * (fmaxf(di * s[i] + bg[i], 0.f) + stv[i]);
        }
    }
    f32x4 va = {acc[0], acc[1], acc[2], acc[3]};
    f32x4 vb = {acc[4], acc[5], acc[6], acc[7]};
    *(f32x4*)&red[slot][c0] = va;
    *(f32x4*)&red[slot][c0 + 4] = vb;
    __syncthreads();
    // 8 b x 128 ch outputs; thread t: b_local = t>>5, 4 consecutive channels
    int bl = tid >> 5;
    int ch0 = (tid & 31) * 4;
    int b2 = blockIdx.x * 8 + bl;
    if (b2 < B) {
        bf16x4 o;
        #pragma unroll
        for (int c = 0; c < 4; c++)
            o[c] = (__bf16)(red[2 * bl][ch0 + c] + red[2 * bl + 1][ch0 + c]);
        *(bf16x4*)(xB + (size_t)b2 * 128 + ch0) = o;
    }
}

// ---- MLP head via MFMA: relu(x@W1+b1) -> relu(@W2+b2) -> @W3+b3 -------------
__global__ __launch_bounds__(256) void k_mlp(const __bf16* __restrict__ xB,
                                             const __bf16* __restrict__ W1t,
                                             const float* __restrict__ b1,
                                             const __bf16* __restrict__ W2t,
                                             const float* __restrict__ b2,
                                             const float* __restrict__ W3,
                                             const float* __restrict__ b3,
                                             float* __restrict__ out, int B) {
    __shared__ __bf16 hs[16][264];
    __shared__ float osum[4][16];
    int wave = threadIdx.x >> 6;
    int lane = threadIdx.x & 63;
    int m = lane & 15;
    int quad = lane >> 4;
    long r0 = (long)blockIdx.x * 16;

    f32x4 acc[4] = {};
    #pragma unroll
    for (int kt = 0; kt < 4; kt++) {
        int k0 = kt * 32 + quad * 8;
        bf16x8 a = *(const bf16x8*)(xB + (r0 + m) * 128 + k0);
        #pragma unroll
        for (int t = 0; t < 4; t++) {
            int n = wave * 64 + t * 16 + m;
            bf16x8 b = *(const bf16x8*)(W1t + (long)n * 128 + k0);
            acc[t] = __builtin_amdgcn_mfma_f32_16x16x32_bf16(a, b, acc[t], 0, 0, 0);
        }
    }
    #pragma unroll
    for (int t = 0; t < 4; t++) {
        int n = wave * 64 + t * 16 + m;
        float bb = b1[n];
        #pragma unroll
        for (int r = 0; r < 4; r++)
            hs[quad * 4 + r][n] = (__bf16)fmaxf(acc[t][r] + bb, 0.f);
    }
    __syncthreads();

    f32x4 acc2[4] = {};
    #pragma unroll
    for (int kt = 0; kt < 8; kt++) {
        int k0 = kt * 32 + quad * 8;
        bf16x8 a = *(const bf16x8*)(&hs[m][k0]);
        #pragma unroll
        for (int t = 0; t < 4; t++) {
            int n = wave * 64 + t * 16 + m;
            bf16x8 b = *(const bf16x8*)(W2t + (long)n * 256 + k0);
            acc2[t] = __builtin_amdgcn_mfma_f32_16x16x32_bf16(a, b, acc2[t], 0, 0, 0);
        }
    }

    float part[4] = {0.f, 0.f, 0.f, 0.f};
    #pragma unroll
    for (int t = 0; t < 4; t++) {
        int n = wave * 64 + t * 16 + m;
        float bb = b2[n], w3 = W3[n];
        #pragma unroll
        for (int r = 0; r < 4; r++)
            part[r] += fmaxf(acc2[t][r] + bb, 0.f) * w3;
    }
    #pragma unroll
    for (int off = 8; off; off >>= 1)
        #pragma unroll
        for (int r = 0; r < 4; r++)
            part[r] += __shfl_down(part[r], off, 16);
    if (m == 0) {
        #pragma unroll
        for (int r = 0; r < 4; r++) osum[wave][quad * 4 + r] = part[r];
    }
    __syncthreads();
    if (threadIdx.x < 16)
        out[r0 + threadIdx.x] = osum[0][threadIdx.x] + osum[1][threadIdx.x] +
                                osum[2][threadIdx.x] + osum[3][threadIdx.x] + b3[0];
}

extern "C" void kernel_launch(void* const* d_in, const int* in_sizes, int n_in,
                              void* d_out, int out_size, void* d_ws, size_t ws_size,
                              hipStream_t stream) {
    const float* state  = (const float*)d_in[0];
    const int*   edge   = (const int*)d_in[1];   // [2, E]: src row then dst row
    const float* action = (const float*)d_in[2];
    const float* W_gcn  = (const float*)d_in[3];
    const float* b_gcn  = (const float*)d_in[4];
    const float* W1     = (const float*)d_in[5];
    const float* b1     = (const float*)d_in[6];
    const float* W2     = (const float*)d_in[7];
    const float* b2     = (const float*)d_in[8];
    const float* W3     = (const float*)d_in[9];
    const float* b3     = (const float*)d_in[10];
    float* out = (float*)d_out;

    int N = in_sizes[0] / 128;
    int E = in_sizes[1] / 2;
    int B = out_size;
    const int* e_src = edge;
    const int* e_dst = edge + E;

    // workspace layout (16B-aligned for the given sizes):
    // xws bf16[N*128] | xB bf16[B*128] | Wgt bf16[128*128] | W1t bf16[256*128]
    // | W2t bf16[256*256] | deg i32[N] | ovfc i32[4] | adj i32[N*8] | ovf i32[2*E]
    __bf16* xws = (__bf16*)d_ws;
    __bf16* xB  = xws + (size_t)N * 128;
    __bf16* Wgt = xB + (size_t)B * 128;
    __bf16* W1t = Wgt + 128 * 128;
    __bf16* W2t = W1t + 256 * 128;
    int*   deg  = (int*)(W2t + 256 * 256);
    int*   ovfc = deg + N;
    int*   adj  = ovfc + 4;
    int*   ovf  = adj + (size_t)N * 8;

    // zero deg + ovfc in one memset
    hipMemsetAsync(deg, 0, ((size_t)N + 4) * sizeof(int), stream);

    k_tconv_all<<<448, 256, 0, stream>>>(W_gcn, W1, W2, Wgt, W1t, W2t);
    k_edges<<<(E + 255) / 256, 256, 0, stream>>>(e_dst, e_src, E, deg, adj, ovfc, ovf);
    k_gemm<<<1024, 256, 0, stream>>>(state, Wgt, deg, xws, N);
    k_readout<<<(B + 7) / 8, 256, 0, stream>>>(deg, adj, ovfc, ovf, xws,
                                               state, b_gcn, action, xB, B);
    k_mlp<<<B / 16, 256, 0, stream>>>(xB, W1t, b1, W2t, b2, W3, b3, out, B);
}

// Round 8
// 612.123 us; speedup vs baseline: 1.4947x; 1.1214x over previous
//
#include <hip/hip_runtime.h>

// Sizes: N=500000, C=128, H=256, A=10, E=600000, B=50000.
// R9:  fixed-K=8 inline adjacency; merged tconv. R10: t_readout=99us (~floor).
// R11: LDS-W gemm at (256,4) REGRESSED (189us): VGPR_Count=64 -> no room for
//   W frags (BUF32+acc32=64) -> serialization; direct 8B stores showed
//   WRITE 178MB (+53) and FETCH +68MB write-allocate => keep LDS-transpose
//   epilogue. MfmaUtil 3.3% => latency-bound, need prefetch depth>=2.
// R12 (this round): k_gemm rebuilt from counters:
//   - W^T in LDS in MFMA-fragment layout wfrag[(t*4+kt)*64+lane] (32KB):
//     ds_read_b128 at base+lane*16 with compile-time offset, stride-1 1KB
//     wave reads (2 lanes/bank = free), zero per-read addr math.
//   - depth-2 A prefetch: 3 named reg buffers, 3-unrolled rotation, clamped
//     tail. No per-tile barrier -> counted vmcnt pipelining works.
//   - __launch_bounds__(256,3): cap 170 VGPR (demand ~155), 3 blocks/CU.
//   - LDS-transpose epilogue kept (1KB coalesced Y stores).

typedef __bf16 bf16x8 __attribute__((ext_vector_type(8)));
typedef __bf16 bf16x4 __attribute__((ext_vector_type(4)));
typedef float f32x4 __attribute__((ext_vector_type(4)));

// ---- per-edge: degree + direct K=8 adjacency write (+ rare overflow) --------
__global__ __launch_bounds__(256) void k_edges(const int* __restrict__ dst,
                                               const int* __restrict__ src, int E,
                                               int* __restrict__ deg,
                                               int* __restrict__ adj,
                                               int* __restrict__ ovfc,
                                               int* __restrict__ ovf) {
    int e = blockIdx.x * 256 + threadIdx.x;
    if (e < E) {
        int d = dst[e];
        int s = src[e];
        int slot = atomicAdd(&deg[d], 1);
        if (slot < 8) {
            adj[(size_t)d * 8 + slot] = s;
        } else {
            int o = atomicAdd(ovfc, 1);
            ovf[2 * o] = d;
            ovf[2 * o + 1] = s;
        }
    }
}

// ---- transpose-convert all three weight matrices in one launch --------------
// ranges: [0,16384) Wgcn 128x128 | [16384,49152) W1 128x256 | rest W2 256x256
__global__ __launch_bounds__(256) void k_tconv_all(const float* __restrict__ Wg,
                                                   const float* __restrict__ W1,
                                                   const float* __restrict__ W2,
                                                   __bf16* __restrict__ Wgt,
                                                   __bf16* __restrict__ W1t,
                                                   __bf16* __restrict__ W2t) {
    int i = blockIdx.x * 256 + threadIdx.x;
    if (i < 16384) {
        int n = i >> 7, k = i & 127;
        Wgt[i] = (__bf16)Wg[k * 128 + n];
    } else if (i < 49152) {
        int j = i - 16384;
        int n = j >> 7, k = j & 127;
        W1t[j] = (__bf16)W1[k * 256 + n];
    } else if (i < 114688) {
        int j = i - 49152;
        int n = j >> 8, k = j & 255;
        W2t[j] = (__bf16)W2[k * 256 + n];
    }
}

// ---- xws = bf16( rsqrt(deg+1)[row] * (state @ W_gcn) )  via MFMA ------------
__global__ __launch_bounds__(256, 3) void k_gemm(const float* __restrict__ X,
                                                 const __bf16* __restrict__ Wt,
                                                 const int* __restrict__ deg,
                                                 __bf16* __restrict__ Y, int N) {
    __shared__ __bf16 wfrag[2048 * 8];     // 32KB: [(t*4+kt)*64+lane] 16B slots
    __shared__ __bf16 st[4][16][136];      // per-wave transpose staging (+8 pad)
    int tid = threadIdx.x;
    int wave = tid >> 6;
    int lane = tid & 63;
    int m = lane & 15;
    int quad = lane >> 4;

    // stage W^T into fragment layout: slot s holds, for lane l=s&63 and
    // (t,kt)=(s>>8, (s>>6)&3), Wt[(t*16+(l&15))*128 + kt*32 + (l>>4)*8 .. +7]
    #pragma unroll
    for (int j = 0; j < 8; j++) {
        int s = tid + j * 256;
        int l = s & 63;
        int tk = s >> 6;
        int t = tk >> 2, kt = tk & 3;
        bf16x8 v = *(const bf16x8*)(Wt + (t * 16 + (l & 15)) * 128 + kt * 32 +
                                    (l >> 4) * 8);
        *(bf16x8*)(wfrag + (size_t)s * 8) = v;
    }
    __syncthreads();

    const long NT = (long)N >> 4;                  // 31250 tiles
    const long g0 = (long)blockIdx.x * 4 + wave;
    const long gs = (long)gridDim.x * 4;
    if (g0 >= NT) return;
    const char* wb = (const char*)wfrag + lane * 16;

    auto loadA = [&](float4* BUF, int& dg, long tile) {
        const float* ap = X + (tile * 16 + m) * 128 + quad * 8;
        #pragma unroll
        for (int kt = 0; kt < 4; kt++) {
            BUF[2 * kt]     = *(const float4*)(ap + kt * 32);
            BUF[2 * kt + 1] = *(const float4*)(ap + kt * 32 + 4);
        }
        dg = deg[tile * 16 + m];
    };

    auto compute = [&](const float4* BUF, int dg, long tile) {
        float dv = rsqrtf((float)dg + 1.0f);
        f32x4 acc[8] = {};
        #pragma unroll
        for (int kt = 0; kt < 4; kt++) {
            float4 lo = BUF[2 * kt], hi = BUF[2 * kt + 1];
            bf16x8 a = {(__bf16)lo.x, (__bf16)lo.y, (__bf16)lo.z, (__bf16)lo.w,
                        (__bf16)hi.x, (__bf16)hi.y, (__bf16)hi.z, (__bf16)hi.w};
            #pragma unroll
            for (int t = 0; t < 8; t++) {
                bf16x8 bf = *(const bf16x8*)(wb + ((t * 4 + kt) << 10));
                acc[t] = __builtin_amdgcn_mfma_f32_16x16x32_bf16(bf, a,
                                                                 acc[t], 0, 0, 0);
            }
        }
        // transpose via per-wave LDS -> 4x 1KB coalesced row stores
        #pragma unroll
        for (int t = 0; t < 8; t++) {
            bf16x4 o;
            #pragma unroll
            for (int r = 0; r < 4; r++) o[r] = (__bf16)(acc[t][r] * dv);
            *(bf16x4*)&st[wave][m][t * 16 + quad * 4] = o;
        }
        asm volatile("s_waitcnt lgkmcnt(0)" ::: "memory");
        __builtin_amdgcn_sched_barrier(0);
        #pragma unroll
        for (int it = 0; it < 4; it++) {
            bf16x8 v = *(const bf16x8*)&st[wave][it * 4 + quad][m * 8];
            *(bf16x8*)(Y + (tile * 16 + it * 4 + quad) * 128 + m * 8) = v;
        }
    };

    auto clampT = [&](long x) { return x < NT ? x : NT - 1; };

    float4 A0[8], A1[8], A2[8];
    int d0, d1, d2;
    long t = g0;
    loadA(A0, d0, t);
    loadA(A1, d1, clampT(t + gs));
    while (true) {
        loadA(A2, d2, clampT(t + 2 * gs));
        compute(A0, d0, t);
        if (t + gs >= NT) break;
        loadA(A0, d0, clampT(t + 3 * gs));
        compute(A1, d1, t + gs);
        if (t + 2 * gs >= NT) break;
        loadA(A1, d1, clampT(t + 4 * gs));
        compute(A2, d2, t + 2 * gs);
        if (t + 3 * gs >= NT) break;
        t += 3 * gs;
    }
}

// ---- fused aggregate + relu + residual + action-weighted readout ------------
// 256 thr = 16 slots x 16 lanes. Block handles 8 b's; slot pair (2s,2s+1)
// covers b_local = s: slot handles nodes b*10 + (slot&1)*5 + k, k<5.
__global__ __launch_bounds__(256) void k_readout(const int* __restrict__ deg,
                                                 const int* __restrict__ adj,
                                                 const int* __restrict__ ovfc,
                                                 const int* __restrict__ ovf,
                                                 const __bf16* __restrict__ xws,
                                                 const float* __restrict__ state,
                                                 const float* __restrict__ bgcn,
                                                 const float* __restrict__ action,
                                                 __bf16* __restrict__ xB, int B) {
    __shared__ float red[16][132];
    int tid = threadIdx.x;
    int slot = tid >> 4;
    int lane16 = tid & 15;
    int c0 = lane16 * 8;
    int b = blockIdx.x * 8 + (slot >> 1);

    float4 bg0 = *(const float4*)(bgcn + c0);
    float4 bg1 = *(const float4*)(bgcn + c0 + 4);
    float bg[8] = {bg0.x, bg0.y, bg0.z, bg0.w, bg1.x, bg1.y, bg1.z, bg1.w};
    float acc[8] = {};

    if (b < B) {
        int nbase = b * 10 + (slot & 1) * 5;
        // prefetch degree + adjacency for all 5 nodes (independent loads)
        int dgs[5];
        int4 aj0[5], aj1[5];
        #pragma unroll
        for (int k = 0; k < 5; k++) {
            int n = nbase + k;
            dgs[k] = deg[n];
            aj0[k] = *(const int4*)(adj + (size_t)n * 8);
            aj1[k] = *(const int4*)(adj + (size_t)n * 8 + 4);
        }
        #pragma unroll
        for (int k = 0; k < 5; k++) {
            int n = nbase + k;
            int dg = dgs[k];
            bf16x8 x = *(const bf16x8*)(xws + (size_t)n * 128 + c0);
            float s[8];
            #pragma unroll
            for (int i = 0; i < 8; i++) s[i] = (float)x[i];
            int nb[8] = {aj0[k].x, aj0[k].y, aj0[k].z, aj0[k].w,
                         aj1[k].x, aj1[k].y, aj1[k].z, aj1[k].w};
            #pragma unroll
            for (int j = 0; j < 8; j++) {
                if (j < dg) {
                    bf16x8 g = *(const bf16x8*)(xws + (size_t)nb[j] * 128 + c0);
                    #pragma unroll
                    for (int i = 0; i < 8; i++) s[i] += (float)g[i];
                }
            }
            if (dg > 8) {             // ~2-3 nodes in 500K: scan overflow list
                int c = *ovfc;
                for (int o = 0; o < c; o++) {
                    if (ovf[2 * o] == n) {
                        bf16x8 g =
                            *(const bf16x8*)(xws + (size_t)ovf[2 * o + 1] * 128 + c0);
                        #pragma unroll
                        for (int i = 0; i < 8; i++) s[i] += (float)g[i];
                    }
                }
            }
            float di = rsqrtf((float)dg + 1.0f);
            float aw = action[n] * 10.f;
            float4 st0 = *(const float4*)(state + (size_t)n * 128 + c0);
            float4 st1 = *(const float4*)(state + (size_t)n * 128 + c0 + 4);
            float stv[8] = {st0.x, st0.y, st0.z, st0.w,
                            st1.x, st1.y, st1.z, st1.w};
            #pragma unroll
            for (int i = 0; i < 8; i++)
                acc[i] += aw * (fmaxf(di * s[i] + bg[i], 0.f) + stv[i]);
        }
    }
    f32x4 va = {acc[0], acc[1], acc[2], acc[3]};
    f32x4 vb = {acc[4], acc[5], acc[6], acc[7]};
    *(f32x4*)&red[slot][c0] = va;
    *(f32x4*)&red[slot][c0 + 4] = vb;
    __syncthreads();
    // 8 b x 128 ch outputs; thread t: b_local = t>>5, 4 consecutive channels
    int bl = tid >> 5;
    int ch0 = (tid & 31) * 4;
    int b2 = blockIdx.x * 8 + bl;
    if (b2 < B) {
        bf16x4 o;
        #pragma unroll
        for (int c = 0; c < 4; c++)
            o[c] = (__bf16)(red[2 * bl][ch0 + c] + red[2 * bl + 1][ch0 + c]);
        *(bf16x4*)(xB + (size_t)b2 * 128 + ch0) = o;
    }
}

// ---- MLP head via MFMA: relu(x@W1+b1) -> relu(@W2+b2) -> @W3+b3 -------------
__global__ __launch_bounds__(256) void k_mlp(const __bf16* __restrict__ xB,
                                             const __bf16* __restrict__ W1t,
                                             const float* __restrict__ b1,
                                             const __bf16* __restrict__ W2t,
                                             const float* __restrict__ b2,
                                             const float* __restrict__ W3,
                                             const float* __restrict__ b3,
                                             float* __restrict__ out, int B) {
    __shared__ __bf16 hs[16][264];
    __shared__ float osum[4][16];
    int wave = threadIdx.x >> 6;
    int lane = threadIdx.x & 63;
    int m = lane & 15;
    int quad = lane >> 4;
    long r0 = (long)blockIdx.x * 16;

    f32x4 acc[4] = {};
    #pragma unroll
    for (int kt = 0; kt < 4; kt++) {
        int k0 = kt * 32 + quad * 8;
        bf16x8 a = *(const bf16x8*)(xB + (r0 + m) * 128 + k0);
        #pragma unroll
        for (int t = 0; t < 4; t++) {
            int n = wave * 64 + t * 16 + m;
            bf16x8 b = *(const bf16x8*)(W1t + (long)n * 128 + k0);
            acc[t] = __builtin_amdgcn_mfma_f32_16x16x32_bf16(a, b, acc[t], 0, 0, 0);
        }
    }
    #pragma unroll
    for (int t = 0; t < 4; t++) {
        int n = wave * 64 + t * 16 + m;
        float bb = b1[n];
        #pragma unroll
        for (int r = 0; r < 4; r++)
            hs[quad * 4 + r][n] = (__bf16)fmaxf(acc[t][r] + bb, 0.f);
    }
    __syncthreads();

    f32x4 acc2[4] = {};
    #pragma unroll
    for (int kt = 0; kt < 8; kt++) {
        int k0 = kt * 32 + quad * 8;
        bf16x8 a = *(const bf16x8*)(&hs[m][k0]);
        #pragma unroll
        for (int t = 0; t < 4; t++) {
            int n = wave * 64 + t * 16 + m;
            bf16x8 b = *(const bf16x8*)(W2t + (long)n * 256 + k0);
            acc2[t] = __builtin_amdgcn_mfma_f32_16x16x32_bf16(a, b, acc2[t], 0, 0, 0);
        }
    }

    float part[4] = {0.f, 0.f, 0.f, 0.f};
    #pragma unroll
    for (int t = 0; t < 4; t++) {
        int n = wave * 64 + t * 16 + m;
        float bb = b2[n], w3 = W3[n];
        #pragma unroll
        for (int r = 0; r < 4; r++)
            part[r] += fmaxf(acc2[t][r] + bb, 0.f) * w3;
    }
    #pragma unroll
    for (int off = 8; off; off >>= 1)
        #pragma unroll
        for (int r = 0; r < 4; r++)
            part[r] += __shfl_down(part[r], off, 16);
    if (m == 0) {
        #pragma unroll
        for (int r = 0; r < 4; r++) osum[wave][quad * 4 + r] = part[r];
    }
    __syncthreads();
    if (threadIdx.x < 16)
        out[r0 + threadIdx.x] = osum[0][threadIdx.x] + osum[1][threadIdx.x] +
                                osum[2][threadIdx.x] + osum[3][threadIdx.x] + b3[0];
}

extern "C" void kernel_launch(void* const* d_in, const int* in_sizes, int n_in,
                              void* d_out, int out_size, void* d_ws, size_t ws_size,
                              hipStream_t stream) {
    const float* state  = (const float*)d_in[0];
    const int*   edge   = (const int*)d_in[1];   // [2, E]: src row then dst row
    const float* action = (const float*)d_in[2];
    const float* W_gcn  = (const float*)d_in[3];
    const float* b_gcn  = (const float*)d_in[4];
    const float* W1     = (const float*)d_in[5];
    const float* b1     = (const float*)d_in[6];
    const float* W2     = (const float*)d_in[7];
    const float* b2     = (const float*)d_in[8];
    const float* W3     = (const float*)d_in[9];
    const float* b3     = (const float*)d_in[10];
    float* out = (float*)d_out;

    int N = in_sizes[0] / 128;
    int E = in_sizes[1] / 2;
    int B = out_size;
    const int* e_src = edge;
    const int* e_dst = edge + E;

    // workspace layout (16B-aligned for the given sizes):
    // xws bf16[N*128] | xB bf16[B*128] | Wgt bf16[128*128] | W1t bf16[256*128]
    // | W2t bf16[256*256] | deg i32[N] | ovfc i32[4] | adj i32[N*8] | ovf i32[2*E]
    __bf16* xws = (__bf16*)d_ws;
    __bf16* xB  = xws + (size_t)N * 128;
    __bf16* Wgt = xB + (size_t)B * 128;
    __bf16* W1t = Wgt + 128 * 128;
    __bf16* W2t = W1t + 256 * 128;
    int*   deg  = (int*)(W2t + 256 * 256);
    int*   ovfc = deg + N;
    int*   adj  = ovfc + 4;
    int*   ovf  = adj + (size_t)N * 8;

    // zero deg + ovfc in one memset
    hipMemsetAsync(deg, 0, ((size_t)N + 4) * sizeof(int), stream);

    k_tconv_all<<<448, 256, 0, stream>>>(W_gcn, W1, W2, Wgt, W1t, W2t);
    k_edges<<<(E + 255) / 256, 256, 0, stream>>>(e_dst, e_src, E, deg, adj, ovfc, ovf);
    k_gemm<<<768, 256, 0, stream>>>(state, Wgt, deg, xws, N);
    k_readout<<<(B + 7) / 8, 256, 0, stream>>>(deg, adj, ovfc, ovf, xws,
                                               state, b_gcn, action, xB, B);
    k_mlp<<<B / 16, 256, 0, stream>>>(xB, W1t, b1, W2t, b2, W3, b3, out, B);
}